// Round 14
// baseline (4160.464 us; speedup 1.0000x reference)
//
#include <hip/hip_runtime.h>
#include <hip/hip_bf16.h>
#include <stdint.h>
#include <stddef.h>

// ---------------------------------------------------------------------------
// Seq2Seq BiGRU: B=256 T=512 F=64 H=256 (2-layer bidir encoder),
// decoder DH=512 2-layer, OSL=20, OUT=2.
//
// Round-16 structure (= r13 + n-major grid for gemmL1):
//  - r13 accounting: scans 2x437us (32-CU serial-scan roofline; cross-CU
//    per-step sync measured >= 2us/step excludes further splitting);
//    dec/gemm/prep below 437us; ~2.6ms invariant harness floor.
//  - gemm_gi K=512: n-major grid (12, 1024). m-major streamed the 134MB
//    xcat A-matrix up to 12x (~1.6GB from L3) because the 12 sharers of
//    each A-tile were 1024 dispatches apart; B (1.57MB total) is L2-
//    resident under ANY order. n-major makes A-tile sharers consecutive
//    -> A streamed ~once. (r5's "n-major hurt" was confounded with a
//    simultaneous decoder change; theory says n-major is strictly right
//    for K=512.) K=64 keeps proven m-major.
//  - All other kernels byte-identical to r13 (4147us, passed).
// ---------------------------------------------------------------------------

typedef __bf16 bf16_t;
typedef bf16_t bf16x8 __attribute__((ext_vector_type(8)));
typedef float  f32x4  __attribute__((ext_vector_type(4)));

#define B_   256
#define T_   512
#define F_   64
#define H_   256
#define G_   768      // 3*H
#define DH_  512
#define DG_  1536     // 3*DH
#define OSL_ 20

__device__ __forceinline__ float sigm(float x) {
    float e = __builtin_amdgcn_exp2f(-1.442695040888963f * x);
    return __builtin_amdgcn_rcpf(1.0f + e);
}
__device__ __forceinline__ float tanh_(float x) {
    float e = __builtin_amdgcn_exp2f(-2.885390081777927f * x);
    return __builtin_amdgcn_rcpf(1.0f + e) * 2.0f - 1.0f;
}

__device__ __forceinline__ bf16x8 load_f32x8_as_bf16(const float* p) {
    f32x4 u = *(const f32x4*)p;
    f32x4 v = *(const f32x4*)(p + 4);
    bf16x8 r;
    r[0]=(bf16_t)u[0]; r[1]=(bf16_t)u[1]; r[2]=(bf16_t)u[2]; r[3]=(bf16_t)u[3];
    r[4]=(bf16_t)v[0]; r[5]=(bf16_t)v[1]; r[6]=(bf16_t)v[2]; r[7]=(bf16_t)v[3];
    return r;
}

// async global->LDS, 16B per lane; LDS dest = wave-uniform base + lane*16
__device__ __forceinline__ void gload_lds16(const void* g, void* l) {
    __builtin_amdgcn_global_load_lds(
        (const __attribute__((address_space(1))) unsigned int*)g,
        (__attribute__((address_space(3))) unsigned int*)l, 16, 0, 0);
}

// ------------------------------- fused prep --------------------------------
__global__ __launch_bounds__(256) void prep_all(
    const float* __restrict__ s0, const float* __restrict__ s1,
    const float* __restrict__ s2, const float* __restrict__ s3,
    const float* __restrict__ s4, const float* __restrict__ s5,
    const float* __restrict__ s6,
    bf16_t* __restrict__ d0, bf16_t* __restrict__ d1, bf16_t* __restrict__ d2,
    bf16_t* __restrict__ d3, bf16_t* __restrict__ d4, bf16_t* __restrict__ d5,
    bf16_t* __restrict__ d6,
    const float* __restrict__ wih0d, const float* __restrict__ fcw,
    const float* __restrict__ fcb, const float* __restrict__ bih0d,
    const float* __restrict__ st, bf16_t* __restrict__ weff,
    float* __restrict__ beff, float* __restrict__ ov,
    unsigned int* __restrict__ bar) {
    int i = blockIdx.x * 256 + threadIdx.x;
    switch (blockIdx.y) {
      case 0: if (i < 2*G_*F_)  d0[i] = (bf16_t)s0[i]; break;
      case 1: if (i < 2*G_*H_)  d1[i] = (bf16_t)s1[i]; break;
      case 2: if (i < 2*G_*DH_) d2[i] = (bf16_t)s2[i]; break;
      case 3: if (i < 2*G_*H_)  d3[i] = (bf16_t)s3[i]; break;
      case 4: if (i < DG_*DH_)  d4[i] = (bf16_t)s4[i]; break;
      case 5: if (i < DG_*DH_)  d5[i] = (bf16_t)s5[i]; break;
      case 6: if (i < DG_*DH_)  d6[i] = (bf16_t)s6[i]; break;
      default: {
        if (i < 1024) bar[i] = 0u;
        if (i < DG_*DH_) {
          int g = i >> 9, k = i & 511;
          float a0 = wih0d[g * 2], a1 = wih0d[g * 2 + 1];
          weff[i] = (bf16_t)(a0 * fcw[k] + a1 * fcw[DH_ + k]);
          if (k == 0) {
            beff[g] = a0 * fcb[0] + a1 * fcb[1] + bih0d[g];
            ov[g]   = a0 * st[0]  + a1 * st[1]  + bih0d[g];
          }
        }
      } break;
    }
}

// --------------------------- gi chunk GEMM ---------------------------------
// K=64 (L0): m-major grid (Tc*2, 12). K=512 (L1): n-major grid (12, Tc*2)
// so the 12 sharers of each A-tile are consecutive -> A streamed ~once;
// B (1.57MB total) is L2-resident under any order.
__global__ __launch_bounds__(256) void gemm_gi(
    const float* __restrict__ x, const bf16_t* __restrict__ xcat,
    const bf16_t* __restrict__ Bt, bf16_t* __restrict__ gi, int t0, int K) {
    __shared__ bf16_t As[128 * 64];
    __shared__ bf16_t Bs[128 * 64];
    int m0, n0;
    if (K == 64) { m0 = blockIdx.x * 128; n0 = blockIdx.y * 128; }
    else         { m0 = blockIdx.y * 128; n0 = blockIdx.x * 128; }
    int tid = threadIdx.x;
    int lane = tid & 63, w = tid >> 6;
    int col = lane & 15, quad = lane >> 4;
    int qm = (w >> 1) * 64, qn = (w & 1) * 64;

    int tl = m0 >> 8;              // local chunk time (constant per block)
    int bbase = m0 & 255;          // batch base (0 or 128)
    int t_real = t0 + tl;
    if (n0 >= 768) t_real = (T_ - 1) - t_real;

    f32x4 acc[4][4] = {};
    for (int k0 = 0; k0 < K; k0 += 64) {
        __syncthreads();
        if (K == 64) {
#pragma unroll
            for (int i = 0; i < 4; i++) {
                int c = i * 256 + tid;
                int m = c >> 3, kc = c & 7;
                int kcs = kc ^ (m & 7);   // XOR swizzle at source
                bf16x8 av = load_f32x8_as_bf16(
                    x + ((size_t)(bbase + m) * T_ + t_real) * F_ + kcs * 8);
                *(bf16x8*)(&As[c * 8]) = av;
                gload_lds16(Bt + (size_t)(n0 + m) * K + k0 + kcs * 8,
                            &Bs[(i * 256 + w * 64) * 8]);
            }
        } else {
#pragma unroll
            for (int i = 0; i < 4; i++) {
                int c = i * 256 + tid;
                int m = c >> 3, kc = c & 7;
                int kcs = kc ^ (m & 7);   // XOR swizzle at source
                gload_lds16(xcat + ((size_t)t_real * B_ + bbase + m) * DH_ + k0 + kcs * 8,
                            &As[(i * 256 + w * 64) * 8]);
                gload_lds16(Bt + (size_t)(n0 + m) * K + k0 + kcs * 8,
                            &Bs[(i * 256 + w * 64) * 8]);
            }
        }
        __syncthreads();
#pragma unroll
        for (int kt = 0; kt < 2; kt++) {
            bf16x8 a[4], b[4];
#pragma unroll
            for (int mt = 0; mt < 4; mt++) {
                int r = qm + mt * 16 + col;
                a[mt] = *(const bf16x8*)(&As[(r * 8 + ((kt * 4 + quad) ^ (r & 7))) * 8]);
                int rn = qn + mt * 16 + col;
                b[mt] = *(const bf16x8*)(&Bs[(rn * 8 + ((kt * 4 + quad) ^ (rn & 7))) * 8]);
            }
#pragma unroll
            for (int mt = 0; mt < 4; mt++)
#pragma unroll
                for (int nt = 0; nt < 4; nt++)
                    acc[mt][nt] = __builtin_amdgcn_mfma_f32_16x16x32_bf16(a[mt], b[nt], acc[mt][nt], 0, 0, 0);
        }
    }
#pragma unroll
    for (int mt = 0; mt < 4; mt++)
#pragma unroll
        for (int nt = 0; nt < 4; nt++)
#pragma unroll
            for (int i = 0; i < 4; i++) {
                int row = m0 + qm + mt * 16 + quad * 4 + i;
                int cg  = n0 + qn + nt * 16 + col;
                gi[(size_t)row * DG_ + cg] = (bf16_t)acc[mt][nt][i];
            }
}

// ------------------------------ GRU scan (chunked) -------------------------
__global__ __launch_bounds__(512) void gru_scan(
    const bf16_t* __restrict__ gi, int t0, int tc,
    const bf16_t* __restrict__ whh,
    const float* __restrict__ bih, const float* __restrict__ bhh,
    float* __restrict__ hstate, bf16_t* __restrict__ y, float* __restrict__ hT) {
    __shared__ bf16_t gi_lds[16 * 768];       // [b][768]
    __shared__ bf16_t h_lds[2 * 16 * 264];    // [par][b][256+8 pad]

    int dir = blockIdx.x >> 4;
    int b0  = (blockIdx.x & 15) * 16;
    int tid = threadIdx.x;
    int w = tid >> 6, lane = tid & 63, col = lane & 15, quad = lane >> 4;

    bf16x8 wf[3][2][8];
    const bf16_t* wbase = whh + (size_t)dir * G_ * H_;
#pragma unroll
    for (int g = 0; g < 3; g++)
#pragma unroll
        for (int nt = 0; nt < 2; nt++) {
            int row = g * 256 + w * 32 + nt * 16 + col;
#pragma unroll
            for (int kt = 0; kt < 8; kt++)
                wf[g][nt][kt] = *(const bf16x8*)(wbase + (size_t)row * H_ + kt * 32 + quad * 8);
        }
    float brz[2][2], bin_[2], bhn[2];
#pragma unroll
    for (int nt = 0; nt < 2; nt++) {
        int j = w * 32 + nt * 16 + col;
        brz[0][nt] = bih[dir * G_ + j] + bhh[dir * G_ + j];
        brz[1][nt] = bih[dir * G_ + 256 + j] + bhh[dir * G_ + 256 + j];
        bin_[nt]   = bih[dir * G_ + 512 + j];
        bhn[nt]    = bhh[dir * G_ + 512 + j];
    }
    int bb[3], oo[3];
#pragma unroll
    for (int it = 0; it < 3; it++) {
        int c = it * 512 + tid;
        bb[it] = c / 96;
        oo[it] = (c % 96) * 8;
    }
    float hold[2][4];
#pragma unroll
    for (int nt = 0; nt < 2; nt++)
#pragma unroll
        for (int i = 0; i < 4; i++) {
            int j = w * 32 + nt * 16 + col;
            hold[nt][i] = t0 ? hstate[dir * 65536 + (b0 + quad * 4 + i) * 256 + j] : 0.0f;
        }
    for (int i = tid; i < 16 * 264; i += 512) {
        int b = i / 264, j = i % 264;
        float v = (t0 && j < 256) ? hstate[dir * 65536 + (b0 + b) * 256 + j] : 0.0f;
        h_lds[i] = (bf16_t)v;
    }
#pragma unroll
    for (int it = 0; it < 3; it++) {
        int c = it * 512 + tid;
        *(bf16x8*)(&gi_lds[c * 8]) =
            *(const bf16x8*)(gi + ((size_t)0 * B_ + b0 + bb[it]) * DG_ + dir * G_ + oo[it]);
    }
    __syncthreads();

    for (int s = 0; s < tc; s++) {
        int par = s & 1;
        int t = t0 + s;
        int sn = (s + 1 < tc) ? (s + 1) : s;

        bf16x8 pg[3];
#pragma unroll
        for (int it = 0; it < 3; it++)
            pg[it] = *(const bf16x8*)(gi + ((size_t)sn * B_ + b0 + bb[it]) * DG_ + dir * G_ + oo[it]);

        f32x4 acc[3][2] = {};
        const bf16_t* hcur = &h_lds[par * 4224];
#pragma unroll
        for (int kt = 0; kt < 8; kt++) {
            bf16x8 af = *(const bf16x8*)(hcur + col * 264 + kt * 32 + quad * 8);
#pragma unroll
            for (int g = 0; g < 3; g++)
#pragma unroll
                for (int nt = 0; nt < 2; nt++)
                    acc[g][nt] = __builtin_amdgcn_mfma_f32_16x16x32_bf16(af, wf[g][nt][kt], acc[g][nt], 0, 0, 0);
        }

        bf16_t* hnext = &h_lds[(par ^ 1) * 4224];
        int tp = dir ? (T_ - 1 - t) : t;
#pragma unroll
        for (int nt = 0; nt < 2; nt++) {
            int j = w * 32 + nt * 16 + col;
#pragma unroll
            for (int i = 0; i < 4; i++) {
                int b = quad * 4 + i;
                float gr = acc[0][nt][i] + (float)gi_lds[b * 768 + j]       + brz[0][nt];
                float gz = acc[1][nt][i] + (float)gi_lds[b * 768 + 256 + j] + brz[1][nt];
                float gn = (float)gi_lds[b * 768 + 512 + j] + bin_[nt];
                float r = sigm(gr), z = sigm(gz);
                float n = tanh_(gn + r * (acc[2][nt][i] + bhn[nt]));
                float hv = (1.0f - z) * n + z * hold[nt][i];
                hold[nt][i] = hv;
                hnext[b * 264 + j] = (bf16_t)hv;
                if (y) y[((size_t)tp * B_ + b0 + b) * DH_ + dir * H_ + j] = (bf16_t)hv;
                if (t == T_ - 1) hT[(size_t)(b0 + b) * DH_ + dir * H_ + j] = hv;
            }
        }
        __syncthreads();
#pragma unroll
        for (int it = 0; it < 3; it++)
            *(bf16x8*)(&gi_lds[(it * 512 + tid) * 8]) = pg[it];
        __syncthreads();
    }
#pragma unroll
    for (int nt = 0; nt < 2; nt++)
#pragma unroll
        for (int i = 0; i < 4; i++) {
            int j = w * 32 + nt * 16 + col;
            hstate[dir * 65536 + (b0 + quad * 4 + i) * 256 + j] = hold[nt][i];
        }
}

// ---------------- persistent decoder, register-resident weights ------------
// 256 WGs x 512 thr = 16 j-slices (s = blockIdx>>4, 32 j) x 16 groups
// (g = blockIdx&15, 16 batch rows). A group's 16 WGs stride 16 in blockIdx
// -> SAME XCD (%8) -> h exchange stays in the XCD-local L2: plain publish
// stores, sc0-only staged loads. 24 weight tiles per WG, 3 per wave,
// loaded once. Full-K per wave -> no reduce; 12KB LDS acc exchange;
// waves 0/1 do gate epilogue + publish (f32 carries there).
// Barrier = RELAXED device RMW + bounded spin (fails visibly, never hangs).

__device__ __forceinline__ void gbar16(unsigned int* cnt) {
    __syncthreads();   // drains vmcnt -> publishes in local L2 before arrival
    if (threadIdx.x == 0) {
        __hip_atomic_fetch_add(cnt, 1u, __ATOMIC_RELAXED, __HIP_MEMORY_SCOPE_AGENT);
        unsigned int s = 0;
        while (__hip_atomic_load(cnt, __ATOMIC_RELAXED, __HIP_MEMORY_SCOPE_AGENT) < 16u
               && ++s < (1u << 20))
            __builtin_amdgcn_s_sleep(1);
    }
    __syncthreads();
}

// stage 16 rows x 512 bf16 (16 KB) with 512 threads: 2 x 16B per thread.
// sc0 = bypass L1, read the shared XCD-local L2 (publishers are intra-XCD).
__device__ __forceinline__ void stage16v(bf16_t* lds, const bf16_t* src) {
    f32x4 v0, v1;
    const char* a0 = (const char*)src + threadIdx.x * 16;
    asm volatile(
        "global_load_dwordx4 %0, %2, off sc0\n\t"
        "global_load_dwordx4 %1, %3, off sc0\n\t"
        "s_waitcnt vmcnt(0)"
        : "=&v"(v0), "=&v"(v1)
        : "v"(a0), "v"(a0 + 8192)
        : "memory");
    {
        int off = threadIdx.x * 16;
        int row = off >> 10;
        int swz = off ^ ((row & 7) << 4);
        *(f32x4*)((char*)lds + swz) = v0;
    }
    {
        int off = 8192 + threadIdx.x * 16;
        int row = off >> 10;
        int swz = off ^ ((row & 7) << 4);
        *(f32x4*)((char*)lds + swz) = v1;
    }
}

__device__ __forceinline__ bf16x8 fragrd(const bf16_t* lds, int kt, int col, int quad) {
    int byte = (col * 1024 + kt * 64 + quad * 16) ^ ((col & 7) << 4);
    return *(const bf16x8*)((const char*)lds + byte);
}

// publish hv as bf16 packed u32 (even-col lanes store j, j+1); plain store
// -> write-through to the XCD-local L2 (readers are intra-XCD, sc0 loads).
__device__ __forceinline__ void publish(bf16_t* dst, int b, int j, float hv, int col) {
    bf16_t hb = (bf16_t)hv;
    unsigned short mb;
    __builtin_memcpy(&mb, &hb, 2);
    unsigned int pv = (unsigned int)__shfl_xor((int)(unsigned int)mb, 1);
    if ((col & 1) == 0) {
        unsigned int word = (unsigned int)mb | (pv << 16);
        *(unsigned int*)((char*)dst + (size_t)(b * DH_ + j) * 2) = word;
    }
}

__global__ __launch_bounds__(512, 2) void dec_persist(
    const bf16_t* __restrict__ weff, const float* __restrict__ beff,
    const float* __restrict__ ov,
    const bf16_t* __restrict__ wdhh0, const float* __restrict__ dbhh0,
    const bf16_t* __restrict__ wdih1, const float* __restrict__ dbih1,
    const bf16_t* __restrict__ wdhh1, const float* __restrict__ dbhh1,
    const float* __restrict__ h0init, const float* __restrict__ h1init,
    bf16_t* hx00, bf16_t* hx01, bf16_t* hx10, bf16_t* hx11,
    float* __restrict__ hist, unsigned int* __restrict__ bar) {
    __shared__ bf16_t sh[16 * 512];   // h0 (persists A<-B)
    __shared__ bf16_t sx[16 * 512];   // h1
    __shared__ f32x4 exch[12 * 64];   // acc exchange (12 tiles x 64 lanes)

    int s  = blockIdx.x >> 4;         // j-slice (partners stride 16 -> same XCD)
    int g  = blockIdx.x & 15;         // batch group
    int js = s * 32;
    int tid = threadIdx.x, w = tid >> 6, lane = tid & 63;
    int col = lane & 15, quad = lane >> 4;

    // ---- prologue: load 3 owned weight tiles into registers ----
    const bf16_t* mats[4] = { wdhh0, weff, wdih1, wdhh1 };
    bf16x8 frg[3][16];
    int tmat[3], texch[3];
#pragma unroll
    for (int sl = 0; sl < 3; ++sl) {
        int idx = w + sl * 8;         // 0..23
        int m = idx / 6, rem = idx - m * 6;
        int gate = rem >> 1, jh = rem & 1;
        tmat[sl] = m;
        texch[sl] = (m & 1) * 6 + rem;   // slot within phase: 0..11
        int row = gate * 512 + js + jh * 16 + col;
        const bf16_t* M = mats[m];
#pragma unroll
        for (int kt = 0; kt < 16; ++kt)
            frg[sl][kt] = *(const bf16x8*)(M + (size_t)row * DH_ + kt * 32 + quad * 8);
    }

    // epilogue-lane constants (valid for w<2; harmless elsewhere)
    int je = js + (w & 1) * 16 + col;
    float b0r = beff[je] + dbhh0[je],        b0z = beff[DH_ + je] + dbhh0[DH_ + je];
    float b0in = beff[2 * DH_ + je],         b0hn = dbhh0[2 * DH_ + je];
    float o0r = ov[je] + dbhh0[je],          o0z = ov[DH_ + je] + dbhh0[DH_ + je];
    float o0in = ov[2 * DH_ + je];
    float b1r = dbih1[je] + dbhh1[je],       b1z = dbih1[DH_ + je] + dbhh1[DH_ + je];
    float b1in = dbih1[2 * DH_ + je],        b1hn = dbhh1[2 * DH_ + je];

    // init: epilogue waves publish initial state, keep f32 carries
    float hold0[4], hold1[4];
    if (w < 2) {
#pragma unroll
        for (int i = 0; i < 4; ++i) {
            int b = g * 16 + quad * 4 + i;
            float v0 = h0init[(size_t)b * DH_ + je];
            float v1 = h1init[(size_t)b * DH_ + je];
            hold0[i] = v0; hold1[i] = v1;
            publish(hx01, b, je, v0, col);
            publish(hx11, b, je, v1, col);
        }
    }
    gbar16(bar + g);   // phase 0: init visible

    int ph = 1;
    for (int t = 0; t < OSL_; ++t) {
        bf16_t* write0 = (t & 1) ? hx01 : hx00;
        bf16_t* read0  = (t & 1) ? hx00 : hx01;
        bf16_t* write1 = (t & 1) ? hx11 : hx10;
        bf16_t* read1  = (t & 1) ? hx10 : hx11;
        bool dox = (t > 0);

        // ---------------- phase A: cell0 ----------------
        // sh holds h0(t-1) (staged in phase B of t-1); stage h1(t-1) only.
        if (t == 0) stage16v(sh, read0 + (size_t)g * 16 * DH_);
        stage16v(sx, read1 + (size_t)g * 16 * DH_);
        __syncthreads();

        {
            f32x4 acc[3] = {};
#pragma unroll
            for (int sl = 0; sl < 3; ++sl) {
                if (tmat[sl] == 0) {            // Whh0 x h0(t-1)
#pragma unroll
                    for (int kt = 0; kt < 16; ++kt)
                        acc[sl] = __builtin_amdgcn_mfma_f32_16x16x32_bf16(
                            fragrd(sh, kt, col, quad), frg[sl][kt], acc[sl], 0, 0, 0);
                } else if (tmat[sl] == 1 && dox) { // Weff x h1(t-1)
#pragma unroll
                    for (int kt = 0; kt < 16; ++kt)
                        acc[sl] = __builtin_amdgcn_mfma_f32_16x16x32_bf16(
                            fragrd(sx, kt, col, quad), frg[sl][kt], acc[sl], 0, 0, 0);
                }
            }
#pragma unroll
            for (int sl = 0; sl < 3; ++sl)
                if (tmat[sl] <= 1) exch[texch[sl] * 64 + lane] = acc[sl];
        }
        __syncthreads();

        if (w < 2) {
            int jh = w;
            f32x4 aR0 = exch[(0 + jh) * 64 + lane];
            f32x4 aZ0 = exch[(2 + jh) * 64 + lane];
            f32x4 aN0 = exch[(4 + jh) * 64 + lane];
            f32x4 aR1 = {}, aZ1 = {}, aN1 = {};
            if (dox) {
                aR1 = exch[(6 + jh) * 64 + lane];
                aZ1 = exch[(8 + jh) * 64 + lane];
                aN1 = exch[(10 + jh) * 64 + lane];
            }
#pragma unroll
            for (int i = 0; i < 4; ++i) {
                int b = g * 16 + quad * 4 + i;
                float r = sigm(aR0[i] + aR1[i] + (dox ? b0r : o0r));
                float z = sigm(aZ0[i] + aZ1[i] + (dox ? b0z : o0z));
                float gin = dox ? (aN1[i] + b0in) : o0in;
                float n = tanh_(gin + r * (aN0[i] + b0hn));
                float hv = (1.0f - z) * n + z * hold0[i];
                hold0[i] = hv;
                publish(write0, b, je, hv, col);
            }
        }
        gbar16(bar + ph * 16 + g); ph++;

        // ---------------- phase B: cell1 ----------------
        stage16v(sh, write0 + (size_t)g * 16 * DH_);   // h0(t)
        __syncthreads();

        {
            f32x4 acc[3] = {};
#pragma unroll
            for (int sl = 0; sl < 3; ++sl) {
                if (tmat[sl] == 2) {            // Wih1 x h0(t)
#pragma unroll
                    for (int kt = 0; kt < 16; ++kt)
                        acc[sl] = __builtin_amdgcn_mfma_f32_16x16x32_bf16(
                            fragrd(sh, kt, col, quad), frg[sl][kt], acc[sl], 0, 0, 0);
                } else if (tmat[sl] == 3) {     // Whh1 x h1(t-1)
#pragma unroll
                    for (int kt = 0; kt < 16; ++kt)
                        acc[sl] = __builtin_amdgcn_mfma_f32_16x16x32_bf16(
                            fragrd(sx, kt, col, quad), frg[sl][kt], acc[sl], 0, 0, 0);
                }
            }
#pragma unroll
            for (int sl = 0; sl < 3; ++sl)
                if (tmat[sl] >= 2) exch[texch[sl] * 64 + lane] = acc[sl];
        }
        __syncthreads();

        if (w < 2) {
            int jh = w;
            f32x4 giR = exch[(0 + jh) * 64 + lane];   // Wih1 (m&1==0)
            f32x4 giZ = exch[(2 + jh) * 64 + lane];
            f32x4 giN = exch[(4 + jh) * 64 + lane];
            f32x4 ghR = exch[(6 + jh) * 64 + lane];   // Whh1 (m&1==1)
            f32x4 ghZ = exch[(8 + jh) * 64 + lane];
            f32x4 ghN = exch[(10 + jh) * 64 + lane];
            float* hist_t = hist + (size_t)t * B_ * DH_;
#pragma unroll
            for (int i = 0; i < 4; ++i) {
                int b = g * 16 + quad * 4 + i;
                float r = sigm(giR[i] + ghR[i] + b1r);
                float z = sigm(giZ[i] + ghZ[i] + b1z);
                float n = tanh_(giN[i] + b1in + r * (ghN[i] + b1hn));
                float hv = (1.0f - z) * n + z * hold1[i];
                hold1[i] = hv;
                hist_t[(size_t)b * DH_ + je] = hv;
                publish(write1, b, je, hv, col);
            }
        }
        if (t < OSL_ - 1) { gbar16(bar + ph * 16 + g); ph++; }
    }
}

// ------------------------------- FC head -----------------------------------
__global__ __launch_bounds__(256) void fc_all(
    const float* __restrict__ hist, const float* __restrict__ fcw,
    const float* __restrict__ fcb, float* __restrict__ out) {
    int t  = blockIdx.x >> 4;
    int b0 = (blockIdx.x & 15) * 16;
    int tid = threadIdx.x;
    int bl = tid >> 4, o = (tid >> 3) & 1, part = tid & 7;
    const float* hp = hist + ((size_t)t * B_ + b0 + bl) * DH_;
    const float* wp = fcw + o * DH_;
    float s = 0.0f;
    for (int k = part * 64; k < part * 64 + 64; k += 4) {
        f32x4 hv = *(const f32x4*)(hp + k);
        f32x4 wv = *(const f32x4*)(wp + k);
        s += hv[0] * wv[0] + hv[1] * wv[1] + hv[2] * wv[2] + hv[3] * wv[3];
    }
    s += __shfl_down(s, 4); s += __shfl_down(s, 2); s += __shfl_down(s, 1);
    if (part == 0) out[(size_t)(b0 + bl) * (OSL_ * 2) + t * 2 + o] = s + fcb[o];
}

// ------------------------------ launcher -----------------------------------

#define OFF_WIH0E 0ull
#define OFF_WHH0E 196608ull
#define OFF_WIH1E 983040ull
#define OFF_WHH1E 2555904ull
#define OFF_WDHH0 3342336ull
#define OFF_WDIH1 4915200ull
#define OFF_WDHH1 6488064ull
#define OFF_WEFF  8060928ull
#define OFF_BEFF  9633792ull
#define OFF_BAR   9641984ull    // 41 phases x 16 groups (zeroed 1024 u32)
#define OFF_OV    9658368ull
#define OFF_H0A   9682944ull
#define OFF_H0B   10207232ull   // hx00 (256 KB) + hx01 (256 KB)
#define OFF_H1A   10731520ull
#define OFF_H1B   11255808ull   // hx10 (256 KB) + hx11 (256 KB)
#define OFF_HST   11780096ull
#define OFF_HIST  12304384ull
#define OFF_XCAT  22790144ull
#define OFF_GI    157007872ull

extern "C" void kernel_launch(void* const* d_in, const int* in_sizes, int n_in,
                              void* d_out, int out_size, void* d_ws, size_t ws_size,
                              hipStream_t stream) {
    const float* x      = (const float*)d_in[0];
    const float* st     = (const float*)d_in[1];
    const float* eWih0  = (const float*)d_in[2];
    const float* eWhh0  = (const float*)d_in[3];
    const float* ebih0  = (const float*)d_in[4];
    const float* ebhh0  = (const float*)d_in[5];
    const float* eWih1  = (const float*)d_in[6];
    const float* eWhh1  = (const float*)d_in[7];
    const float* ebih1  = (const float*)d_in[8];
    const float* ebhh1  = (const float*)d_in[9];
    const float* dWih0  = (const float*)d_in[10];
    const float* dWhh0  = (const float*)d_in[11];
    const float* dbih0  = (const float*)d_in[12];
    const float* dbhh0  = (const float*)d_in[13];
    const float* dWih1  = (const float*)d_in[14];
    const float* dWhh1  = (const float*)d_in[15];
    const float* dbih1  = (const float*)d_in[16];
    const float* dbhh1  = (const float*)d_in[17];
    const float* fcW    = (const float*)d_in[18];
    const float* fcb    = (const float*)d_in[19];

    char* ws = (char*)d_ws;
    bf16_t* wih0e = (bf16_t*)(ws + OFF_WIH0E);
    bf16_t* whh0e = (bf16_t*)(ws + OFF_WHH0E);
    bf16_t* wih1e = (bf16_t*)(ws + OFF_WIH1E);
    bf16_t* whh1e = (bf16_t*)(ws + OFF_WHH1E);
    bf16_t* wdhh0 = (bf16_t*)(ws + OFF_WDHH0);
    bf16_t* wdih1 = (bf16_t*)(ws + OFF_WDIH1);
    bf16_t* wdhh1 = (bf16_t*)(ws + OFF_WDHH1);
    bf16_t* weff  = (bf16_t*)(ws + OFF_WEFF);
    float*  beff  = (float*)(ws + OFF_BEFF);
    unsigned int* bar = (unsigned int*)(ws + OFF_BAR);
    float*  ovp   = (float*)(ws + OFF_OV);
    float*  h0init = (float*)(ws + OFF_H0A);
    float*  h1init = (float*)(ws + OFF_H1A);
    bf16_t* hx00  = (bf16_t*)(ws + OFF_H0B);
    bf16_t* hx01  = (bf16_t*)(ws + OFF_H0B + 262144ull);
    bf16_t* hx10  = (bf16_t*)(ws + OFF_H1B);
    bf16_t* hx11  = (bf16_t*)(ws + OFF_H1B + 262144ull);
    float*  hstate = (float*)(ws + OFF_HST);
    float*  hist  = (float*)(ws + OFF_HIST);
    bf16_t* xcat  = (bf16_t*)(ws + OFF_XCAT);
    bf16_t* gi    = (bf16_t*)(ws + OFF_GI);

    int Tc = 512;
    while (Tc > 8 && OFF_GI + (unsigned long long)Tc * 786432ull > (unsigned long long)ws_size)
        Tc >>= 1;
    int nch = T_ / Tc;

    prep_all<<<dim3(3072, 8), 256, 0, stream>>>(
        eWih0, eWhh0, eWih1, eWhh1, dWhh0, dWih1, dWhh1,
        wih0e, whh0e, wih1e, whh1e, wdhh0, wdih1, wdhh1,
        dWih0, fcW, fcb, dbih0, st, weff, beff, ovp, bar);

    for (int c = 0; c < nch; c++) {
        gemm_gi<<<dim3(Tc * 2, 12), 256, 0, stream>>>(x, nullptr, wih0e, gi, c * Tc, 64);
        gru_scan<<<32, 512, 0, stream>>>(gi, c * Tc, Tc, whh0e, ebih0, ebhh0, hstate, xcat, h0init);
    }
    for (int c = 0; c < nch; c++) {
        gemm_gi<<<dim3(12, Tc * 2), 256, 0, stream>>>(nullptr, xcat, wih1e, gi, c * Tc, 512);
        gru_scan<<<32, 512, 0, stream>>>(gi, c * Tc, Tc, whh1e, ebih1, ebhh1, hstate, nullptr, h1init);
    }

    dec_persist<<<256, 512, 0, stream>>>(weff, beff, ovp,
                                         wdhh0, dbhh0, wdih1, dbih1, wdhh1, dbhh1,
                                         h0init, h1init,
                                         hx00, hx01, hx10, hx11,
                                         hist, bar);

    fc_all<<<OSL_ * 16, 256, 0, stream>>>(hist, fcW, fcb, (float*)d_out);
}